// Round 1
// baseline (245.641 us; speedup 1.0000x reference)
//
#include <hip/hip_runtime.h>

// out[t, :] = (1/32) * sum_{j=0..31} features[idx[t, j], :]
// features: [N_NODES, 128] f32, idx: [N_TARGETS, 32] i32, out: [N_TARGETS, 128] f32

constexpr int D = 128;          // feature dim
constexpr int S = 32;           // samples per target
constexpr int D2 = D / 2;       // float2 elements per row (= 64 = one wave)

__global__ __launch_bounds__(256) void Aggregator_20710332301461_kernel(
    const float* __restrict__ feat,
    const int* __restrict__ idx,
    float* __restrict__ out,
    int n_targets)
{
    const int lane = threadIdx.x & 63;
    const int wave_in_block = threadIdx.x >> 6;
    const int waves_per_block = blockDim.x >> 6;
    const int wave_global = blockIdx.x * waves_per_block + wave_in_block;
    const int n_waves = gridDim.x * waves_per_block;

    const float2* __restrict__ f2 = reinterpret_cast<const float2*>(feat);
    float2* __restrict__ o2 = reinterpret_cast<float2*>(out);

    for (int t = wave_global; t < n_targets; t += n_waves) {
        // Preload the 32 neighbor indices into lanes 0..31, broadcast via shfl.
        int myidx = 0;
        if (lane < S) myidx = idx[t * S + lane];

        float ax = 0.f, ay = 0.f;
        #pragma unroll
        for (int j = 0; j < S; ++j) {
            int r = __shfl(myidx, j);
            float2 v = f2[(long)r * D2 + lane];
            ax += v.x;
            ay += v.y;
        }
        float2 res;
        res.x = ax * (1.f / S);
        res.y = ay * (1.f / S);
        o2[(long)t * D2 + lane] = res;
    }
}

extern "C" void kernel_launch(void* const* d_in, const int* in_sizes, int n_in,
                              void* d_out, int out_size, void* d_ws, size_t ws_size,
                              hipStream_t stream) {
    const float* feat = (const float*)d_in[0];
    const int* idx = (const int*)d_in[1];
    float* out = (float*)d_out;

    const int n_targets = out_size / D;   // 100,000

    // Full-occupancy grid: 256 CUs x 32 waves/CU = 8192 waves = 2048 blocks @256.
    const int block = 256;
    const int waves_per_block = block / 64;
    int grid = (n_targets + waves_per_block - 1) / waves_per_block;
    if (grid > 2048) grid = 2048;

    Aggregator_20710332301461_kernel<<<grid, block, 0, stream>>>(feat, idx, out, n_targets);
}